// Round 1
// baseline (97.993 us; speedup 1.0000x reference)
//
#include <hip/hip_runtime.h>
#include <stdint.h>

#define K 64
#define N 128
#define BS 128
#define NPAIRS 2016
#define BLOCK 256

typedef unsigned long long u64;

__global__ __launch_bounds__(BLOCK) void osd_kernel(const float* __restrict__ llrs,
                                                    const float* __restrict__ gm,
                                                    float* __restrict__ out) {
    __shared__ float lam[N];        // clipped llr, original order
    __shared__ float keyAbs[N];     // |lam|, gets sorted
    __shared__ int   keyIdx[N];     // original index, gets sorted (= idx_sort)
    __shared__ float lamSort[N];    // lam in sorted order
    __shared__ u64   gmcols[N];     // gm column bitsets (original column order)
    __shared__ u64   cols[N];       // post-elimination columns (sorted order)
    __shared__ int   pivots[K];
    __shared__ int   mark[N];
    __shared__ int   idxp[K];       // non-pivot sorted-columns, ascending
    __shared__ u64   Pmask[K];      // parity part of eliminated row i (64 bits)
    __shared__ double sigHi[K];     // flip-score weight for parity position m
    __shared__ double Tsc[K];       // single-flip delta score
    __shared__ int   offs[K + 1];   // triangular offsets for pair decode
    __shared__ double redS[BLOCK];
    __shared__ int   redId[BLOCK];
    __shared__ u64   cLo, cHi, cbLo, cbHi;

    const int tid = threadIdx.x;
    const int item = blockIdx.x;
    const float* llr = llrs + item * N;

    // ---- Phase 0: load/clip llr; pack gm columns into bitsets ----
    if (tid < N) {
        float v = llr[tid];
        v = fminf(fmaxf(v, -100.0f), 100.0f);
        lam[tid] = v;
        keyAbs[tid] = fabsf(v);
        keyIdx[tid] = tid;
        u64 w = 0;
        for (int i = 0; i < K; ++i)
            w |= (u64)(gm[i * N + tid] != 0.0f) << i;
        gmcols[tid] = w;
    }
    __syncthreads();

    // ---- Phase 1: bitonic sort 128 elems by (|lam| desc, idx asc) — stable-equivalent ----
    for (int k2 = 2; k2 <= N; k2 <<= 1) {
        for (int j = k2 >> 1; j > 0; j >>= 1) {
            if (tid < N) {
                int l = tid ^ j;
                if (l > tid) {
                    float aA = keyAbs[tid], aB = keyAbs[l];
                    int iA = keyIdx[tid], iB = keyIdx[l];
                    bool before = (aA > aB) || (aA == aB && iA < iB);
                    bool dirAsc = ((tid & k2) == 0);
                    if (before != dirAsc) {
                        keyAbs[tid] = aB; keyAbs[l] = aA;
                        keyIdx[tid] = iB; keyIdx[l] = iA;
                    }
                }
            }
            __syncthreads();
        }
    }
    if (tid < N) lamSort[tid] = lam[keyIdx[tid]];
    __syncthreads();

    // ---- Phase 2: GF(2) Gaussian elimination, column-parallel in wave 0 ----
    // lane j owns sorted-columns j (c0) and j+64 (c1); bit r of a column = row r entry
    if (tid < 64) {
        u64 c0 = gmcols[keyIdx[tid]];
        u64 c1 = gmcols[keyIdx[tid + 64]];
        for (int i = 0; i < K; ++i) {
            int b0 = (int)((c0 >> i) & 1ull);
            int b1 = (int)((c1 >> i) & 1ull);
            u64 m0 = __ballot(b0);
            u64 m1 = __ballot(b1);
            int p;
            if (m0) p = __builtin_ctzll(m0);
            else if (m1) p = 64 + __builtin_ctzll(m1);
            else p = 0; // unreachable for full-rank gm; mimics argmax-of-zeros
            u64 v0 = __shfl(c0, p & 63);
            u64 v1 = __shfl(c1, p & 63);
            u64 colp = (p < 64) ? v0 : v1;
            u64 msk = colp & ~(1ull << i);
            if (b0) c0 ^= msk;
            if (b1) c1 ^= msk;
            if (tid == 0) pivots[i] = p;
        }
        cols[tid] = c0;
        cols[tid + 64] = c1;
    }
    __syncthreads();

    // ---- Phase 3: pivot marks, parity column list, pair-decode offsets ----
    if (tid < N) mark[tid] = 0;
    __syncthreads();
    if (tid < K) mark[pivots[tid]] = 1;
    __syncthreads();
    if (tid == 0) {
        int cnt = 0;
        for (int j = 0; j < N; ++j) if (!mark[j]) idxp[cnt++] = j;
    }
    if (tid <= K) offs[tid] = tid * 63 - (tid * (tid - 1)) / 2;
    __syncthreads();

    // ---- Phase 4: parity row masks, u_hat, baseline codeword (cLo|cHi) ----
    if (tid < 64) {
        u64 P = 0;
        for (int m = 0; m < K; ++m)
            P |= ((cols[idxp[m]] >> tid) & 1ull) << m;  // broadcast LDS reads
        Pmask[tid] = P;
        int uh = lamSort[pivots[tid]] > 0.0f;
        u64 lo = __ballot(uh);
        u64 x = uh ? P : 0ull;
        for (int off = 32; off >= 1; off >>= 1) x ^= __shfl_xor(x, off);
        if (tid == 0) { cLo = lo; cHi = x; }
    }
    __syncthreads();

    // ---- Phase 5: sigma weights for parity bits; single-flip scores T ----
    if (tid < K) {
        float lp = lamSort[idxp[tid]];
        int cbit = (int)((cHi >> tid) & 1ull);
        sigHi[tid] = cbit ? -(double)lp : (double)lp;
    }
    __syncthreads();
    if (tid < K) {
        double W = 0.0;
        u64 P = Pmask[tid];
        while (P) {
            int m = __builtin_ctzll(P);
            W += sigHi[m];
            P &= P - 1;
        }
        // sigma for MRB position a is -|lam_mrb[a]| = -keyAbs[pivots[a]] (sorted abs)
        Tsc[tid] = W - (double)keyAbs[pivots[tid]];
    }
    __syncthreads();

    // ---- Phase 6: scan base + 64 singles + 2016 pairs; keep (max deltaS, min id) ----
    double bestS = 0.0; int bestId = 0;  // id 0 = baseline
    if (tid < K) {
        double s = Tsc[tid];
        if (s > bestS) { bestS = s; bestId = 1 + tid; }  // ids 1..64 = singles
    }
    for (int pid = tid; pid < NPAIRS; pid += BLOCK) {
        int lo = 0, hi = 63;
        while (lo < hi) { int mid = (lo + hi + 1) >> 1; if (offs[mid] <= pid) lo = mid; else hi = mid - 1; }
        int a = lo;
        int b = a + 1 + (pid - offs[a]);
        u64 inter = Pmask[a] & Pmask[b];
        double W2 = 0.0;
        while (inter) {
            int m = __builtin_ctzll(inter);
            W2 += sigHi[m];
            inter &= inter - 1;
        }
        double s = Tsc[a] + Tsc[b] - 2.0 * W2;
        int id = 65 + pid;  // ids 65.. = pairs (lex order)
        if (s > bestS || (s == bestS && id < bestId)) { bestS = s; bestId = id; }
    }
    redS[tid] = bestS; redId[tid] = bestId;
    __syncthreads();
    for (int off = BLOCK / 2; off >= 1; off >>= 1) {
        if (tid < off) {
            double s2 = redS[tid + off]; int i2 = redId[tid + off];
            if (s2 > redS[tid] || (s2 == redS[tid] && i2 < redId[tid])) {
                redS[tid] = s2; redId[tid] = i2;
            }
        }
        __syncthreads();
    }

    // ---- Phase 7: materialize best codeword, scatter to original column order ----
    if (tid == 0) {
        int id = redId[0];
        u64 flo = 0, fhi = 0;
        if (id >= 1 && id <= 64) {
            int a = id - 1; flo = 1ull << a; fhi = Pmask[a];
        } else if (id >= 65) {
            int pid = id - 65;
            int lo = 0, hi = 63;
            while (lo < hi) { int mid = (lo + hi + 1) >> 1; if (offs[mid] <= pid) lo = mid; else hi = mid - 1; }
            int a = lo; int b = a + 1 + (pid - offs[a]);
            flo = (1ull << a) | (1ull << b);
            fhi = Pmask[a] ^ Pmask[b];
        }
        cbLo = cLo ^ flo; cbHi = cHi ^ fhi;
    }
    __syncthreads();
    if (tid < N) {
        int bit, mrbcol;
        if (tid < K) { bit = (int)((cbLo >> tid) & 1ull); mrbcol = pivots[tid]; }
        else { bit = (int)((cbHi >> (tid - K)) & 1ull); mrbcol = idxp[tid - K]; }
        int orig = keyIdx[mrbcol];              // idx_total[tid]
        out[item * N + orig] = (float)bit;      // inverse permutation = scatter
    }
}

extern "C" void kernel_launch(void* const* d_in, const int* in_sizes, int n_in,
                              void* d_out, int out_size, void* d_ws, size_t ws_size,
                              hipStream_t stream) {
    const float* llrs = (const float*)d_in[0];
    const float* gm   = (const float*)d_in[1];
    float* out = (float*)d_out;
    (void)in_sizes; (void)n_in; (void)out_size; (void)d_ws; (void)ws_size;
    osd_kernel<<<BS, BLOCK, 0, stream>>>(llrs, gm, out);
}

// Round 2
// 74.741 us; speedup vs baseline: 1.3111x; 1.3111x over previous
//
#include <hip/hip_runtime.h>
#include <stdint.h>

#define K 64
#define N 128
#define BS 128
#define NPAIRS 2016
#define NCAND (64 + NPAIRS)
#define BLOCK 256

typedef unsigned long long u64;
typedef unsigned int u32;

__device__ inline u64 bcast64(u64 v, int lane) {
    // wave-uniform lane broadcast via readlane (scalar path, cheaper than bpermute)
    int lo = __builtin_amdgcn_readlane((int)(u32)v, lane);
    int hi = __builtin_amdgcn_readlane((int)(u32)(v >> 32), lane);
    return ((u64)(u32)hi << 32) | (u32)lo;
}

__device__ inline int nth_set_bit(u64 m, int i) {
    // position of i-th (0-based) set bit; pure ALU
    int pos = 0;
#pragma unroll
    for (int w = 32; w >= 1; w >>= 1) {
        u64 mask = (1ull << w) - 1ull;
        int c = __popcll(m & mask);
        if (i >= c) { i -= c; m >>= w; pos += w; }
    }
    return pos;
}

__global__ __launch_bounds__(BLOCK) void osd_kernel(const float* __restrict__ llrs,
                                                    const float* __restrict__ gm,
                                                    float* __restrict__ out) {
    __shared__ float  lam[N];        // clipped llr, original order
    __shared__ u64    skey[N];       // packed sort key: (~absbits)<<32 | idx  (asc == abs desc, idx asc)
    __shared__ int    keyIdx[N];     // sorted original indices (= idx_sort)
    __shared__ float  lamSort[N];    // lam in sorted order
    __shared__ u64    gmcols[N];     // gm column bitsets (original column order)
    __shared__ u64    cols[N];       // post-elimination columns (sorted order)
    __shared__ int    pivotsLds[K];
    __shared__ int    idxpLds[K];
    __shared__ int    markLds[N];
    __shared__ u64    PmaskLds[K];   // parity mask of MRB row a
    __shared__ float  absMrb[K];     // |lam| of MRB position a
    __shared__ double sigLds[K];     // flip weight for parity position m
    __shared__ double table[8 * 256]; // byte-wise weighted popcount table
    __shared__ double redS[4];
    __shared__ int    redId[4];
    __shared__ u64    cScal[4];      // cLo, cHi, cbLo, cbHi

    const int tid = threadIdx.x;
    const int item = blockIdx.x;
    const float* llr = llrs + item * N;

    // ---- Phase 0: load/clip llr, pack sort keys; pack gm columns (256 threads) ----
    if (tid < N) {
        float v = llr[tid];
        v = fminf(fmaxf(v, -100.0f), 100.0f);
        lam[tid] = v;
        u32 ab = __float_as_uint(fabsf(v));
        skey[tid] = ((u64)(0xFFFFFFFFu - ab) << 32) | (u32)tid;
    }
    {
        int col = tid & 127, rh = tid >> 7;   // rh selects rows [0,32) or [32,64)
        u32 w = 0;
#pragma unroll
        for (int i = 0; i < 32; ++i)
            w |= (u32)(gm[(rh * 32 + i) * N + col] != 0.0f) << i;
        ((u32*)gmcols)[col * 2 + rh] = w;     // little-endian: rh=0 -> low dword
    }
    __syncthreads();  // barrier 1

    // ---- Wave-0 mega-phase: sort, elimination, pivots/idxp, Pmask, baseline ----
    if (tid < 64) {
        // -- barrier-free bitonic sort of 128 packed keys (lane handles pair (i, i|j)) --
        for (int k2 = 2; k2 <= N; k2 <<= 1) {
            for (int j = k2 >> 1; j >= 1; j >>= 1) {
                int i = ((tid & ~(j - 1)) << 1) | (tid & (j - 1));
                int ip = i | j;
                u64 a = skey[i], b = skey[ip];
                bool asc = ((i & k2) == 0);
                bool sw = asc ? (a > b) : (a < b);
                if (sw) { skey[i] = b; skey[ip] = a; }
                // same-wave LDS ordering: next stage's reads see these writes
            }
        }
        // decode sorted keys
        {
            u64 kv = skey[tid];      int ix = (int)(u32)kv;
            keyIdx[tid] = ix;        lamSort[tid] = lam[ix];
            kv = skey[tid + 64];     ix = (int)(u32)kv;
            keyIdx[tid + 64] = ix;   lamSort[tid + 64] = lam[ix];
        }

        // -- GF(2) elimination, column-parallel; lane owns sorted cols tid, tid+64 --
        u64 c0 = gmcols[keyIdx[tid]];
        u64 c1 = gmcols[keyIdx[tid + 64]];
        int pivotReg = 0;
        for (int i = 0; i < K; ++i) {
            int b0 = (int)((c0 >> i) & 1ull);
            int b1 = (int)((c1 >> i) & 1ull);
            u64 m0 = __ballot(b0);
            u64 m1 = __ballot(b1);
            int p = m0 ? __builtin_ctzll(m0) : (m1 ? 64 + __builtin_ctzll(m1) : 0);
            u64 colp = (p < 64) ? bcast64(c0, p & 63) : bcast64(c1, p & 63);
            u64 msk = colp & ~(1ull << i);
            if (b0) c0 ^= msk;
            if (b1) c1 ^= msk;
            pivotReg = (i == tid) ? p : pivotReg;
        }
        cols[tid] = c0;
        cols[tid + 64] = c1;
        pivotsLds[tid] = pivotReg;

        // -- pivot marks -> nonpivot masks -> idxp via ALU nth-set-bit --
        markLds[tid] = 0; markLds[tid + 64] = 0;
        markLds[pivotReg] = 1;                       // distinct scatter (full rank)
        u64 pm0 = __ballot(markLds[tid] != 0);
        u64 pm1 = __ballot(markLds[tid + 64] != 0);
        u64 nm0 = ~pm0, nm1 = ~pm1;
        int c0n = __popcll(nm0);
        int idxpReg = (tid < c0n) ? nth_set_bit(nm0, tid)
                                  : 64 + nth_set_bit(nm1, tid - c0n);
        idxpLds[tid] = idxpReg;

        // -- Pmask via ballot transpose: P[tid] bit m = colsP[m] bit tid --
        u64 cp = cols[idxpReg];                       // lane m holds parity column m
        u64 P = 0;
#pragma unroll
        for (int x = 0; x < 64; ++x) {
            u64 bx = __ballot((int)((cp >> x) & 1ull));  // bit j = colsP[j] bit x
            P = (x == tid) ? bx : P;
        }
        PmaskLds[tid] = P;

        // -- baseline codeword: u_hat on MRB, parity via xor-reduce --
        float lpv = lamSort[pivotReg];
        int uh = lpv > 0.0f;
        absMrb[tid] = fabsf(lpv);
        u64 cLo = __ballot(uh);
        u64 x = uh ? P : 0ull;
#pragma unroll
        for (int off = 32; off >= 1; off >>= 1) x ^= __shfl_xor(x, off);
        u64 cHi = x;   // full value in all lanes

        // -- flip weights for parity positions --
        float lp = lamSort[idxpReg];
        int cbit = (int)((cHi >> tid) & 1ull);
        sigLds[tid] = cbit ? -(double)lp : (double)lp;

        if (tid == 0) { cScal[0] = cLo; cScal[1] = cHi; }
    }
    __syncthreads();  // barrier 2

    // ---- Byte table: T[pos][v] = sum of sig over set bits of byte v at byte pos ----
    {
        int pos = tid >> 5, grp = tid & 31;
        double sg[8];
#pragma unroll
        for (int j = 0; j < 8; ++j) sg[j] = sigLds[pos * 8 + j];
        int g = grp << 3;
        double base = 0.0;
#pragma unroll
        for (int j = 3; j < 8; ++j) if ((g >> j) & 1) base += sg[j];
#pragma unroll
        for (int e = 0; e < 8; ++e) {
            double s = base;
            if (e & 1) s += sg[0];
            if (e & 2) s += sg[1];
            if (e & 4) s += sg[2];
            table[pos * 256 + g + e] = s;
        }
    }
    __syncthreads();  // barrier 3

    // ---- Candidate scan: 64 singles + 2016 pairs; S = W(mask) - penalty ----
    double bestS = 0.0; int bestId = 0;  // baseline id 0, S = 0
    for (int c = tid; c < NCAND; c += BLOCK) {
        u64 mask; double pen; int id;
        if (c < 64) {
            mask = PmaskLds[c];
            pen = (double)absMrb[c];
            id = 1 + c;
        } else {
            int pid = c - 64;
            int lo = 0, hi = 62;   // ALU-only binary search on closed-form offs(a)
            while (lo < hi) {
                int mid = (lo + hi + 1) >> 1;
                int o = mid * 63 - ((mid * (mid - 1)) >> 1);
                if (o <= pid) lo = mid; else hi = mid - 1;
            }
            int a = lo;
            int oa = a * 63 - ((a * (a - 1)) >> 1);
            int b = a + 1 + (pid - oa);
            mask = PmaskLds[a] ^ PmaskLds[b];
            pen = (double)absMrb[a] + (double)absMrb[b];
            id = 65 + pid;
        }
        double W = 0.0;
#pragma unroll
        for (int p2 = 0; p2 < 8; ++p2)
            W += table[p2 * 256 + (int)((mask >> (p2 * 8)) & 255ull)];
        double s = W - pen;
        if (s > bestS || (s == bestS && id < bestId)) { bestS = s; bestId = id; }
    }
    // per-wave shfl reduction (max S, min id)
#pragma unroll
    for (int off = 32; off >= 1; off >>= 1) {
        double s2 = __shfl_xor(bestS, off);
        int i2 = __shfl_xor(bestId, off);
        if (s2 > bestS || (s2 == bestS && i2 < bestId)) { bestS = s2; bestId = i2; }
    }
    if ((tid & 63) == 0) { redS[tid >> 6] = bestS; redId[tid >> 6] = bestId; }
    __syncthreads();  // barrier 4

    // ---- Winner -> best codeword masks ----
    if (tid == 0) {
        double bS = redS[0]; int bi = redId[0];
        for (int w = 1; w < 4; ++w) {
            double s2 = redS[w]; int i2 = redId[w];
            if (s2 > bS || (s2 == bS && i2 < bi)) { bS = s2; bi = i2; }
        }
        u64 flo = 0, fhi = 0;
        if (bi >= 1 && bi <= 64) {
            int a = bi - 1; flo = 1ull << a; fhi = PmaskLds[a];
        } else if (bi >= 65) {
            int pid = bi - 65;
            int lo = 0, hi = 62;
            while (lo < hi) {
                int mid = (lo + hi + 1) >> 1;
                int o = mid * 63 - ((mid * (mid - 1)) >> 1);
                if (o <= pid) lo = mid; else hi = mid - 1;
            }
            int a = lo;
            int oa = a * 63 - ((a * (a - 1)) >> 1);
            int b = a + 1 + (pid - oa);
            flo = (1ull << a) | (1ull << b);
            fhi = PmaskLds[a] ^ PmaskLds[b];
        }
        cScal[2] = cScal[0] ^ flo;
        cScal[3] = cScal[1] ^ fhi;
    }
    __syncthreads();  // barrier 5

    // ---- Scatter to original column order (inverse permutation) ----
    if (tid < N) {
        u64 cbLo = cScal[2], cbHi = cScal[3];
        int bit, mrbcol;
        if (tid < K) { bit = (int)((cbLo >> tid) & 1ull); mrbcol = pivotsLds[tid]; }
        else         { bit = (int)((cbHi >> (tid - K)) & 1ull); mrbcol = idxpLds[tid - K]; }
        out[item * N + keyIdx[mrbcol]] = (float)bit;
    }
}

extern "C" void kernel_launch(void* const* d_in, const int* in_sizes, int n_in,
                              void* d_out, int out_size, void* d_ws, size_t ws_size,
                              hipStream_t stream) {
    const float* llrs = (const float*)d_in[0];
    const float* gm   = (const float*)d_in[1];
    float* out = (float*)d_out;
    (void)in_sizes; (void)n_in; (void)out_size; (void)d_ws; (void)ws_size;
    osd_kernel<<<BS, BLOCK, 0, stream>>>(llrs, gm, out);
}

// Round 3
// 70.720 us; speedup vs baseline: 1.3856x; 1.0568x over previous
//
#include <hip/hip_runtime.h>
#include <stdint.h>

#define K 64
#define N 128
#define BS 128
#define NPAIRS 2016
#define BLOCK 256

typedef unsigned long long u64;
typedef unsigned int u32;

__device__ inline u64 bcast64(u64 v, int lane) {
    // wave-uniform lane broadcast via readlane (lane index is in SGPR)
    int lo = __builtin_amdgcn_readlane((int)(u32)v, lane);
    int hi = __builtin_amdgcn_readlane((int)(u32)(v >> 32), lane);
    return ((u64)(u32)hi << 32) | (u32)lo;
}

__device__ inline int nth_set_bit(u64 m, int i) {
    // position of i-th (0-based) set bit; pure ALU
    int pos = 0;
#pragma unroll
    for (int w = 32; w >= 1; w >>= 1) {
        u64 mask = (1ull << w) - 1ull;
        int c = __popcll(m & mask);
        if (i >= c) { i -= c; m >>= w; pos += w; }
    }
    return pos;
}

// weighted popcount via byte table: 8 independent LDS reads, pairwise-tree sum
__device__ inline double wsum(const double* __restrict__ table, u64 mask) {
    double t0 = table[0 * 256 + (int)(mask & 255ull)];
    double t1 = table[1 * 256 + (int)((mask >> 8) & 255ull)];
    double t2 = table[2 * 256 + (int)((mask >> 16) & 255ull)];
    double t3 = table[3 * 256 + (int)((mask >> 24) & 255ull)];
    double t4 = table[4 * 256 + (int)((mask >> 32) & 255ull)];
    double t5 = table[5 * 256 + (int)((mask >> 40) & 255ull)];
    double t6 = table[6 * 256 + (int)((mask >> 48) & 255ull)];
    double t7 = table[7 * 256 + (int)((mask >> 56) & 255ull)];
    return ((t0 + t1) + (t2 + t3)) + ((t4 + t5) + (t6 + t7));
}

// largest a in [0,62] with offs(a) <= pid, offs(a) = a*63 - a(a-1)/2; fixed-trip branchless
__device__ inline int pair_decode_a(int pid) {
    int a = 0;
#pragma unroll
    for (int st = 32; st >= 1; st >>= 1) {
        int cd = a + st;
        int o = cd * 63 - ((cd * (cd - 1)) >> 1);
        if (cd <= 62 && o <= pid) a = cd;
    }
    return a;
}

__global__ __launch_bounds__(BLOCK) void osd_kernel(const float* __restrict__ llrs,
                                                    const float* __restrict__ gm,
                                                    float* __restrict__ out) {
    __shared__ float  lam[N];        // clipped llr, original order
    __shared__ u64    skey[N];       // packed key: (~absbits)<<32 | idx (asc == abs desc, idx asc)
    __shared__ int    keyIdx[N];     // sorted original indices (= idx_sort)
    __shared__ float  lamSort[N];    // lam in sorted order
    __shared__ u64    gmcols[N];     // gm column bitsets (original column order)
    __shared__ u64    cols[N];       // post-elimination columns (sorted order)
    __shared__ int    pivotsLds[K];
    __shared__ int    idxpLds[K];
    __shared__ int    markLds[N];
    __shared__ u64    PmaskLds[K];   // parity mask of MRB row a
    __shared__ float  absMrb[K];     // |lam| of MRB position a
    __shared__ double sigLds[K];     // flip weight for parity position m
    __shared__ double table[8 * 256]; // byte-wise weighted popcount table
    __shared__ double redS[4];
    __shared__ int    redId[4];
    __shared__ u64    cScal[4];      // cLo, cHi, cbLo, cbHi

    const int tid = threadIdx.x;
    const int item = blockIdx.x;
    const float* llr = llrs + item * N;

    // ---- Phase 0: load/clip llr, build packed sort keys; pack gm columns ----
    if (tid < N) {
        float v = llr[tid];
        v = fminf(fmaxf(v, -100.0f), 100.0f);
        lam[tid] = v;
        u32 ab = __float_as_uint(fabsf(v));
        skey[tid] = ((u64)(0xFFFFFFFFu - ab) << 32) | (u32)tid;
    }
    {
        int col = tid & 127, rh = tid >> 7;   // rh: rows [0,32) or [32,64)
        u32 w = 0;
#pragma unroll
        for (int i = 0; i < 32; ++i)
            w |= (u32)(gm[(rh * 32 + i) * N + col] != 0.0f) << i;
        ((u32*)gmcols)[col * 2 + rh] = w;     // little-endian: rh=0 -> low dword
    }
    __syncthreads();  // barrier 1

    // ---- Phase 1: rank sort (128 threads, broadcast LDS reads, fully pipelined) ----
    if (tid < N) {
        u64 myk = skey[tid];
        int rank = 0;
#pragma unroll 16
        for (int j = 0; j < N; ++j)
            rank += (int)(skey[j] < myk);
        int ix = (int)(u32)myk;
        keyIdx[rank] = ix;           // ranks are a permutation (keys distinct)
        lamSort[rank] = lam[ix];
    }
    __syncthreads();  // barrier 2

    // ---- Wave-0 mega-phase: elimination, pivots/idxp, Pmask, baseline, sig ----
    if (tid < 64) {
        // GF(2) elimination, column-parallel; lane owns sorted cols tid, tid+64
        u64 c0 = gmcols[keyIdx[tid]];
        u64 c1 = gmcols[keyIdx[tid + 64]];
        int pivotReg = 0;
        for (int i = 0; i < K; ++i) {
            int b0 = (int)((c0 >> i) & 1ull);
            int b1 = (int)((c1 >> i) & 1ull);
            u64 m0 = __ballot(b0);
            u64 m1 = __ballot(b1);
            int p = m0 ? __builtin_ctzll(m0) : (m1 ? 64 + __builtin_ctzll(m1) : 0);
            u64 colp = (p < 64) ? bcast64(c0, p & 63) : bcast64(c1, p & 63);
            u64 msk = colp & ~(1ull << i);
            if (b0) c0 ^= msk;
            if (b1) c1 ^= msk;
            pivotReg = (i == tid) ? p : pivotReg;
        }
        cols[tid] = c0;
        cols[tid + 64] = c1;
        pivotsLds[tid] = pivotReg;

        // pivot marks -> nonpivot masks -> idxp via ALU nth-set-bit
        markLds[tid] = 0; markLds[tid + 64] = 0;
        markLds[pivotReg] = 1;                       // distinct scatter (full rank)
        u64 pm0 = __ballot(markLds[tid] != 0);
        u64 pm1 = __ballot(markLds[tid + 64] != 0);
        u64 nm0 = ~pm0, nm1 = ~pm1;
        int c0n = __popcll(nm0);
        int idxpReg = (tid < c0n) ? nth_set_bit(nm0, tid)
                                  : 64 + nth_set_bit(nm1, tid - c0n);
        idxpLds[tid] = idxpReg;

        // Pmask via ballot transpose: P[tid] bit m = colsP[m] bit tid
        u64 cp = cols[idxpReg];                      // lane m holds parity column m
        u64 P = 0;
#pragma unroll
        for (int x = 0; x < 64; ++x) {
            u64 bx = __ballot((int)((cp >> x) & 1ull));
            P = (x == tid) ? bx : P;
        }
        PmaskLds[tid] = P;

        // baseline codeword: u_hat on MRB, parity via xor-reduce
        float lpv = lamSort[pivotReg];
        int uh = lpv > 0.0f;
        absMrb[tid] = fabsf(lpv);
        u64 cLo = __ballot(uh);
        u64 x = uh ? P : 0ull;
#pragma unroll
        for (int off = 32; off >= 1; off >>= 1) x ^= __shfl_xor(x, off);
        u64 cHi = x;

        // flip weights for parity positions
        float lp = lamSort[idxpReg];
        int cbit = (int)((cHi >> tid) & 1ull);
        sigLds[tid] = cbit ? -(double)lp : (double)lp;

        if (tid == 0) { cScal[0] = cLo; cScal[1] = cHi; }
    }
    __syncthreads();  // barrier 3

    // ---- Byte table: T[pos][v] = sum of sig over set bits of byte v at pos ----
    {
        int pos = tid >> 5, grp = tid & 31;
        double sg[8];
#pragma unroll
        for (int j = 0; j < 8; ++j) sg[j] = sigLds[pos * 8 + j];
        int g = grp << 3;
        double base = 0.0;
#pragma unroll
        for (int j = 3; j < 8; ++j) if ((g >> j) & 1) base += sg[j];
#pragma unroll
        for (int e = 0; e < 8; ++e) {
            double s = base;
            if (e & 1) s += sg[0];
            if (e & 2) s += sg[1];
            if (e & 4) s += sg[2];
            table[pos * 256 + g + e] = s;
        }
    }
    __syncthreads();  // barrier 4

    // ---- Candidate scan: baseline(0) + 64 singles + 2016 pairs ----
    double bestS = 0.0; int bestId = 0;  // baseline id 0, S = 0
    if (tid < 64) {
        double s = wsum(table, PmaskLds[tid]) - (double)absMrb[tid];
        if (s > bestS) { bestS = s; bestId = 1 + tid; }
    }
#pragma unroll
    for (int it = 0; it < 8; ++it) {
        int pid = tid + it * BLOCK;
        if (pid < NPAIRS) {
            int a = pair_decode_a(pid);
            int oa = a * 63 - ((a * (a - 1)) >> 1);
            int b = a + 1 + (pid - oa);
            u64 mask = PmaskLds[a] ^ PmaskLds[b];
            double s = wsum(table, mask) - (double)absMrb[a] - (double)absMrb[b];
            int id = 65 + pid;
            if (s > bestS || (s == bestS && id < bestId)) { bestS = s; bestId = id; }
        }
    }
    // per-wave shfl reduction (max S, min id)
#pragma unroll
    for (int off = 32; off >= 1; off >>= 1) {
        double s2 = __shfl_xor(bestS, off);
        int i2 = __shfl_xor(bestId, off);
        if (s2 > bestS || (s2 == bestS && i2 < bestId)) { bestS = s2; bestId = i2; }
    }
    if ((tid & 63) == 0) { redS[tid >> 6] = bestS; redId[tid >> 6] = bestId; }
    __syncthreads();  // barrier 5

    // ---- Winner -> best codeword masks ----
    if (tid == 0) {
        double bS = redS[0]; int bi = redId[0];
        for (int w = 1; w < 4; ++w) {
            double s2 = redS[w]; int i2 = redId[w];
            if (s2 > bS || (s2 == bS && i2 < bi)) { bS = s2; bi = i2; }
        }
        u64 flo = 0, fhi = 0;
        if (bi >= 1 && bi <= 64) {
            int a = bi - 1; flo = 1ull << a; fhi = PmaskLds[a];
        } else if (bi >= 65) {
            int pid = bi - 65;
            int a = pair_decode_a(pid);
            int oa = a * 63 - ((a * (a - 1)) >> 1);
            int b = a + 1 + (pid - oa);
            flo = (1ull << a) | (1ull << b);
            fhi = PmaskLds[a] ^ PmaskLds[b];
        }
        cScal[2] = cScal[0] ^ flo;
        cScal[3] = cScal[1] ^ fhi;
    }
    __syncthreads();  // barrier 6

    // ---- Scatter to original column order (inverse permutation) ----
    if (tid < N) {
        u64 cbLo = cScal[2], cbHi = cScal[3];
        int bit, mrbcol;
        if (tid < K) { bit = (int)((cbLo >> tid) & 1ull); mrbcol = pivotsLds[tid]; }
        else         { bit = (int)((cbHi >> (tid - K)) & 1ull); mrbcol = idxpLds[tid - K]; }
        out[item * N + keyIdx[mrbcol]] = (float)bit;
    }
}

extern "C" void kernel_launch(void* const* d_in, const int* in_sizes, int n_in,
                              void* d_out, int out_size, void* d_ws, size_t ws_size,
                              hipStream_t stream) {
    const float* llrs = (const float*)d_in[0];
    const float* gm   = (const float*)d_in[1];
    float* out = (float*)d_out;
    (void)in_sizes; (void)n_in; (void)out_size; (void)d_ws; (void)ws_size;
    osd_kernel<<<BS, BLOCK, 0, stream>>>(llrs, gm, out);
}